// Round 6
// baseline (145.095 us; speedup 1.0000x reference)
//
#include <hip/hip_runtime.h>

#define MAXLEN 20
#define DIM 1024
#define NB 16384

// clang-native vector types (HIP_vector_type float4 is rejected by
// __builtin_nontemporal_load/store).
typedef float vf4 __attribute__((ext_vector_type(4)));
typedef int   vi4 __attribute__((ext_vector_type(4)));

// One block per row. 256 threads; thread i owns 16B slot i of D=1024.
// alpha=0.5 -> weights are exact powers of two: w[t] = 2^-(L-1-t) / (2*(1-2^-L)).
// Tokens 0..3 are loaded UNCONDITIONALLY at block start (row storage is always
// MAXLEN long, so in-bounds; invalid tokens get weight exactly 0) so 4 KB/wave
// is in flight from cycle 0, fully overlapping the mask->L dependency chain.
__global__ __launch_bounds__(256, 8) void tdap_kernel(
    const float* __restrict__ x,     // [NB, MAXLEN, DIM]
    const int*   __restrict__ mask,  // [NB, MAXLEN]
    float*       __restrict__ out)   // [NB, DIM]
{
    const int b   = blockIdx.x;
    const int tid = threadIdx.x;  // 0..255

    const vf4* xp = reinterpret_cast<const vf4*>(x + (size_t)b * MAXLEN * DIM) + tid;

    // Speculative loads of tokens 0..3 (always in-bounds), issued before the
    // mask sum is even computable.
    vf4 v0 = __builtin_nontemporal_load(&xp[0 * (DIM / 4)]);
    vf4 v1 = __builtin_nontemporal_load(&xp[1 * (DIM / 4)]);
    vf4 v2 = __builtin_nontemporal_load(&xp[2 * (DIM / 4)]);
    vf4 v3 = __builtin_nontemporal_load(&xp[3 * (DIM / 4)]);

    // Mask row: 80 B, lane-uniform address -> scalar loads.
    const vi4* mrow = reinterpret_cast<const vi4*>(mask + (size_t)b * MAXLEN);
    vi4 m0 = mrow[0], m1 = mrow[1], m2 = mrow[2], m3 = mrow[3], m4 = mrow[4];
    const int L = m0.x + m0.y + m0.z + m0.w
                + m1.x + m1.y + m1.z + m1.w
                + m2.x + m2.y + m2.z + m2.w
                + m3.x + m3.y + m3.z + m3.w
                + m4.x + m4.y + m4.z + m4.w;

    // norm = sum_{k=0}^{L-1} 0.5^k = 2*(1-2^-L), exact in fp32 for L<=20.
    const float inv_norm = 1.0f / (2.0f * (1.0f - ldexpf(1.0f, -L)));
    const float w0 = ldexpf(1.0f, -(L - 1)) * inv_norm;  // weight of token 0

    // Token j (j=0..3) has true weight w0*2^j; accumulator aj carries epilogue
    // scale 2^j, so feed each with multiplier w0 -- zeroed when j >= L.
    vf4 a0 = w0 * v0;                          // L >= 1 always
    vf4 a1 = (1 < L ? w0 : 0.0f) * v1;
    vf4 a2 = (2 < L ? w0 : 0.0f) * v2;
    vf4 a3 = (3 < L ? w0 : 0.0f) * v3;

    float w = 16.0f * w0;  // weight of token 4
    int t = 4;
    // Main: 4 tokens/iter; token t+j carries weight w*2^j, folded in epilogue.
    for (; t + 4 <= L; t += 4) {
        vf4 u0 = __builtin_nontemporal_load(&xp[(size_t)(t + 0) * (DIM / 4)]);
        vf4 u1 = __builtin_nontemporal_load(&xp[(size_t)(t + 1) * (DIM / 4)]);
        vf4 u2 = __builtin_nontemporal_load(&xp[(size_t)(t + 2) * (DIM / 4)]);
        vf4 u3 = __builtin_nontemporal_load(&xp[(size_t)(t + 3) * (DIM / 4)]);
        a0 += w * u0;
        a1 += w * u1;
        a2 += w * u2;
        a3 += w * u3;
        w *= 16.0f;  // exact power-of-two scale
    }
    for (; t < L; ++t) {  // tail 0..3 tokens, multiplier 1 -> a0
        vf4 u = __builtin_nontemporal_load(&xp[(size_t)t * (DIM / 4)]);
        a0 += w * u;
        w *= 2.0f;
    }

    // acc = a0 + 2*a1 + 4*a2 + 8*a3 (exact power-of-two scales).
    vf4 acc = a0 + 2.0f * a1 + 4.0f * a2 + 8.0f * a3;

    __builtin_nontemporal_store(acc, reinterpret_cast<vf4*>(out + (size_t)b * DIM) + tid);
}

extern "C" void kernel_launch(void* const* d_in, const int* in_sizes, int n_in,
                              void* d_out, int out_size, void* d_ws, size_t ws_size,
                              hipStream_t stream) {
    const float* x    = (const float*)d_in[0];
    const int*   mask = (const int*)d_in[1];
    float*       out  = (float*)d_out;
    tdap_kernel<<<NB, 256, 0, stream>>>(x, mask, out);
}

// Round 7
// 141.449 us; speedup vs baseline: 1.0258x; 1.0258x over previous
//
#include <hip/hip_runtime.h>

#define MAXLEN 20
#define DIM 1024
#define NB 16384

// clang-native vector types (HIP_vector_type float4 is rejected by
// __builtin_nontemporal_load/store).
typedef float vf4 __attribute__((ext_vector_type(4)));
typedef int   vi4 __attribute__((ext_vector_type(4)));

// One block per row. 256 threads; thread i owns 16B slot i of D=1024.
// alpha=0.5 -> weights are exact powers of two: w[t] = 2^-(L-1-t) / (2*(1-2^-L)).
// Token 0 is always valid (L >= 1), so its load is issued BEFORE the mask sum
// is consumed -- the mask->L->x dependency chain and the first x-load latency
// overlap instead of serializing. Nontemporal on the zero-reuse x/out streams.
// NOTE (R6 lesson): speculatively loading tokens 1..3 as well costs +2.6%
// bytes and exactly +2.5% time -- the kernel is purely BW-bound; do not
// trade bytes for latency.
__global__ __launch_bounds__(256, 8) void tdap_kernel(
    const float* __restrict__ x,     // [NB, MAXLEN, DIM]
    const int*   __restrict__ mask,  // [NB, MAXLEN]
    float*       __restrict__ out)   // [NB, DIM]
{
    const int b   = blockIdx.x;
    const int tid = threadIdx.x;  // 0..255

    const vf4* xp = reinterpret_cast<const vf4*>(x + (size_t)b * MAXLEN * DIM) + tid;

    // Speculative token-0 load (always in-bounds), concurrent with mask loads.
    vf4 v0 = __builtin_nontemporal_load(&xp[0]);

    // Mask row: 80 B, lane-uniform address -> scalar loads.
    const vi4* mrow = reinterpret_cast<const vi4*>(mask + (size_t)b * MAXLEN);
    vi4 m0 = mrow[0], m1 = mrow[1], m2 = mrow[2], m3 = mrow[3], m4 = mrow[4];
    const int L = m0.x + m0.y + m0.z + m0.w
                + m1.x + m1.y + m1.z + m1.w
                + m2.x + m2.y + m2.z + m2.w
                + m3.x + m3.y + m3.z + m3.w
                + m4.x + m4.y + m4.z + m4.w;

    // norm = sum_{k=0}^{L-1} 0.5^k = 2*(1-2^-L), exact in fp32 for L<=20.
    const float inv_norm = 1.0f / (2.0f * (1.0f - ldexpf(1.0f, -L)));
    float w = ldexpf(1.0f, -(L - 1)) * inv_norm;  // weight of token 0

    vf4 a0 = w * v0;
    vf4 a1 = (vf4)0.0f;
    vf4 a2 = (vf4)0.0f;
    vf4 a3 = (vf4)0.0f;

    int t = 1;
    w *= 2.0f;  // weight of token 1
    // Main: 4 tokens/iter; token t+j carries weight w*2^j, folded in epilogue.
    for (; t + 4 <= L; t += 4) {
        vf4 u0 = __builtin_nontemporal_load(&xp[(size_t)(t + 0) * (DIM / 4)]);
        vf4 u1 = __builtin_nontemporal_load(&xp[(size_t)(t + 1) * (DIM / 4)]);
        vf4 u2 = __builtin_nontemporal_load(&xp[(size_t)(t + 2) * (DIM / 4)]);
        vf4 u3 = __builtin_nontemporal_load(&xp[(size_t)(t + 3) * (DIM / 4)]);
        a0 += w * u0;
        a1 += w * u1;
        a2 += w * u2;
        a3 += w * u3;
        w *= 16.0f;  // exact power-of-two scale
    }
    for (; t < L; ++t) {  // tail 0..3 tokens, multiplier 1 -> a0
        vf4 u = __builtin_nontemporal_load(&xp[(size_t)t * (DIM / 4)]);
        a0 += w * u;
        w *= 2.0f;
    }

    // acc = a0 + 2*a1 + 4*a2 + 8*a3 (exact power-of-two scales).
    vf4 acc = a0 + 2.0f * a1 + 4.0f * a2 + 8.0f * a3;

    __builtin_nontemporal_store(acc, reinterpret_cast<vf4*>(out + (size_t)b * DIM) + tid);
}

extern "C" void kernel_launch(void* const* d_in, const int* in_sizes, int n_in,
                              void* d_out, int out_size, void* d_ws, size_t ws_size,
                              hipStream_t stream) {
    const float* x    = (const float*)d_in[0];
    const int*   mask = (const int*)d_in[1];
    float*       out  = (float*)d_out;
    tdap_kernel<<<NB, 256, 0, stream>>>(x, mask, out);
}